// Round 6
// baseline (475.358 us; speedup 1.0000x reference)
//
#include <hip/hip_runtime.h>
#include <stdint.h>

typedef __attribute__((ext_vector_type(4))) int i32x4;

#define QLIM 127.0f

// ---------------- fused quantize: x and w in one dispatch ----------------
__global__ __launch_bounds__(256) void quantize_fused(
    const float4* __restrict__ x, const float4* __restrict__ w,
    int* __restrict__ q,                       // qx (nx4 ints) then qw
    const float* __restrict__ amax, const float* __restrict__ amax_w,
    long nx4, long ntot4)
{
    const float sx = QLIM / amax[0];
    const float sw = QLIM / amax_w[0];
    const long stride = (long)gridDim.x * blockDim.x;
    for (long i = (long)blockIdx.x * blockDim.x + threadIdx.x; i < ntot4; i += stride) {
        const bool isx = i < nx4;
        const float4 v = isx ? x[i] : w[i - nx4];
        const float s  = isx ? sx : sw;
        float a0 = rintf(fminf(fmaxf(v.x * s, -QLIM), QLIM));
        float a1 = rintf(fminf(fmaxf(v.y * s, -QLIM), QLIM));
        float a2 = rintf(fminf(fmaxf(v.z * s, -QLIM), QLIM));
        float a3 = rintf(fminf(fmaxf(v.w * s, -QLIM), QLIM));
        q[i] = ((int)a0 & 255) | (((int)a1 & 255) << 8) |
               (((int)a2 & 255) << 16) | (((int)a3 & 255) << 24);
    }
}

// ---------------- 256x256 2-phase-per-Ktile i8 GEMM (T2+T3+T4+T5) ----------------
// C[M][N] = A[M][K] * B[N][K]^T, fp32 epilogue via LDS-transposed float4 stores.
// LDS per matrix: [buf(2)][kh(2)][row(256)][64B], swizzle: phys_col = col ^ (((row>>1)&3)<<4)
// (verified conflict-free R3: SQ_LDS_BANK_CONFLICT = 0). Staged via linear
// global_load_lds from inverse-swizzled global source (rule #21).
// Phase = (t, kk): 12 ds_read_b128 + stage 1 kh of both matrices + barrier +
// lgkmcnt(0) + sched_barrier + setprio + 32 MFMA. Stagger: ph0 stages kh1(t+1),
// ph1 stages kh0(t+2); vmcnt(4) once per tile (0 in last 2 tiles).
// vmcnt ledger (per wave, 2 ops/STAGE): prologue 12 -> vmcnt(4) retires tile0's 8.
// Tile t entry invariant: kh0+kh1 of t landed, outstanding = kh0(t+1) [4 ops];
// ph0 +4 (kh1(t+1)) -> 8; ph1 +4 (kh0(t+2)) -> 12, vmcnt(4) retires kh0+kh1(t+1). QED.

#define STAGE(mat, tt, kh) do {                                              \
    if ((tt) < nt) {                                                         \
        const size_t go = (size_t)((tt) * 128 + (kh) * 64);                  \
        const int ld = ((((tt) & 1) << 15) | ((kh) << 14));                  \
        __builtin_amdgcn_global_load_lds(                                    \
            (const __attribute__((address_space(1))) void*)(mat##Src + go),  \
            (__attribute__((address_space(3))) void*)(lds + mat##Dst + ld),  \
            16, 0, 0);                                                       \
        __builtin_amdgcn_global_load_lds(                                    \
            (const __attribute__((address_space(1))) void*)(mat##Src + go + rowStep), \
            (__attribute__((address_space(3))) void*)(lds + mat##Dst + ld + 8192),    \
            16, 0, 0);                                                       \
    }                                                                        \
} while (0)

__global__ __launch_bounds__(512, 2) void gemm_i8_2phase(
    const signed char* __restrict__ A,   // qx [M][K]
    const signed char* __restrict__ B,   // qw [N][K]
    const float* __restrict__ bias,
    const float* __restrict__ amax,
    const float* __restrict__ amax_w,
    float* __restrict__ C,
    int M, int N, int K)
{
    __shared__ signed char lds[131072];  // A: 0..64K, B: 64K..128K

    const int tid  = threadIdx.x;        // 0..511
    const int wid  = tid >> 6;           // 0..7
    const int lane = tid & 63;
    const int wr   = wid >> 2;           // 0..1  A-row half (128 rows)
    const int wc   = wid & 3;            // 0..3  B-col quarter (64 rows)
    const int bn   = blockIdx.x;
    const int bm   = blockIdx.y;
    const int nt   = K >> 7;             // K-tiles of 128 bytes

    const int fr   = lane & 15;
    const int fk   = (lane >> 4) << 4;
    const int fswz = ((fr >> 1) & 3) << 4;

    const int aRd = (wr * 128 + fr) * 64 + (fk ^ fswz);
    const int bRd = 65536 + (wc * 64 + fr) * 64 + (fk ^ fswz);

    // staging: thread t -> row (t>>2) (+128 for 2nd load), 16B chunk (t&3),
    // global col pre-inverse-swizzled so linear LDS dest holds swizzled layout
    const int srow = tid >> 2;                                  // 0..127
    const int csw  = (((tid & 3) ^ ((tid >> 3) & 3)) << 4);
    const signed char* aSrc = A + (size_t)(bm * 256 + srow) * K + csw;
    const signed char* bSrc = B + (size_t)(bn * 256 + srow) * K + csw;
    const size_t rowStep = (size_t)128 * K;
    const int aDst = wid << 10;
    const int bDst = 65536 + (wid << 10);

    i32x4 acc[8][4] = {};

    // ---- prologue: tile0 both kh + tile1 kh0 ----
    STAGE(a, 0, 0); STAGE(b, 0, 0); STAGE(a, 0, 1); STAGE(b, 0, 1);
    STAGE(a, 1, 0); STAGE(b, 1, 0);
    asm volatile("s_waitcnt vmcnt(4)" ::: "memory");   // retire tile0's 8 loads
    __builtin_amdgcn_s_barrier();

#pragma unroll 1
    for (int t = 0; t < nt; ++t) {
        const int bb = (t & 1) << 15;
        const signed char* pa = lds + bb + aRd;
        const signed char* pb = lds + bb + bRd;
        i32x4 af[8], bf[4];

        // ---------- phase 0: kk=0, all 32 MFMA ----------
#pragma unroll
        for (int mm = 0; mm < 8; ++mm) af[mm] = *(const i32x4*)(pa + mm * 1024);
#pragma unroll
        for (int nn = 0; nn < 4; ++nn) bf[nn] = *(const i32x4*)(pb + nn * 1024);
        STAGE(a, t + 1, 1);
        STAGE(b, t + 1, 1);
        __builtin_amdgcn_s_barrier();
        asm volatile("s_waitcnt lgkmcnt(0)" ::: "memory");
        __builtin_amdgcn_sched_barrier(0);
        __builtin_amdgcn_s_setprio(1);
#pragma unroll
        for (int mm = 0; mm < 8; ++mm)
#pragma unroll
            for (int nn = 0; nn < 4; ++nn)
                acc[mm][nn] = __builtin_amdgcn_mfma_i32_16x16x64_i8(af[mm], bf[nn], acc[mm][nn], 0, 0, 0);
        __builtin_amdgcn_s_setprio(0);
        __builtin_amdgcn_s_barrier();

        // ---------- phase 1: kk=1, all 32 MFMA ----------
#pragma unroll
        for (int mm = 0; mm < 8; ++mm) af[mm] = *(const i32x4*)(pa + 16384 + mm * 1024);
#pragma unroll
        for (int nn = 0; nn < 4; ++nn) bf[nn] = *(const i32x4*)(pb + 16384 + nn * 1024);
        STAGE(a, t + 2, 0);
        STAGE(b, t + 2, 0);
        __builtin_amdgcn_s_barrier();
        asm volatile("s_waitcnt lgkmcnt(0)" ::: "memory");
        __builtin_amdgcn_sched_barrier(0);
        __builtin_amdgcn_s_setprio(1);
#pragma unroll
        for (int mm = 0; mm < 8; ++mm)
#pragma unroll
            for (int nn = 0; nn < 4; ++nn)
                acc[mm][nn] = __builtin_amdgcn_mfma_i32_16x16x64_i8(af[mm], bf[nn], acc[mm][nn], 0, 0, 0);
        __builtin_amdgcn_s_setprio(0);
        if (t < nt - 2) asm volatile("s_waitcnt vmcnt(4)" ::: "memory");
        else            asm volatile("s_waitcnt vmcnt(0)" ::: "memory");
        __builtin_amdgcn_s_barrier();
    }

    // ---- epilogue: acc -> LDS (swizzled) -> float4 global stores ----
    // LDS as [128 rows][256 fp32] = exactly 128KB; 2 rounds (m-halves).
    // phys_col = col ^ ((lrow&12)<<2). R5 BUG was storing to the PHYSICAL
    // column; the value read at phys (c4) is the output for LOGICAL group
    // (i&63) -> store to bn*256 + (i&63)*4.
    const float sa  = QLIM / amax[0];
    const float sw  = QLIM / amax_w[0];
    const float inv = 1.0f / (sa * sw);
    float* ldsf = (float*)lds;
    const int rsub = (lane >> 4) << 2;

#pragma unroll 1
    for (int h = 0; h < 2; ++h) {
        __builtin_amdgcn_s_barrier();
#pragma unroll
        for (int mq = 0; mq < 4; ++mq) {
#pragma unroll
            for (int n = 0; n < 4; ++n) {
                const int colc = wc * 64 + n * 16 + fr;
                const float bv = bias[bn * 256 + colc];
#pragma unroll
                for (int r = 0; r < 4; ++r) {
                    const int lrow = wr * 64 + mq * 16 + rsub + r;
                    const int pc = colc ^ ((lrow & 12) << 2);
                    ldsf[lrow * 256 + pc] = (float)acc[h * 4 + mq][n][r] * inv + bv;
                }
            }
        }
        __builtin_amdgcn_s_barrier();
#pragma unroll
        for (int it = 0; it < 16; ++it) {
            const int i = it * 512 + tid;
            const int lrow = i >> 6;
            const int lc = i & 63;               // LOGICAL float4 group
            const int pc4 = lc ^ (lrow & 12);    // physical float4 group
            const float4 v = *(const float4*)(ldsf + lrow * 256 + pc4 * 4);
            const int grow = bm * 256 + (lrow >> 6) * 128 + h * 64 + (lrow & 63);
            *(float4*)(C + (size_t)grow * N + bn * 256 + lc * 4) = v;
        }
    }
}

extern "C" void kernel_launch(void* const* d_in, const int* in_sizes, int n_in,
                              void* d_out, int out_size, void* d_ws, size_t ws_size,
                              hipStream_t stream) {
    const float* x      = (const float*)d_in[0];
    const float* w      = (const float*)d_in[1];
    const float* bias   = (const float*)d_in[2];
    const float* amax   = (const float*)d_in[3];
    const float* amax_w = (const float*)d_in[4];
    float* out = (float*)d_out;

    const int N = in_sizes[2];                 // 4096
    const int K = in_sizes[1] / N;             // 4096
    const int M = in_sizes[0] / K;             // 8192

    signed char* qx = (signed char*)d_ws;      // M*K (32 MB)
    signed char* qw = qx + (size_t)M * K;      // N*K (16 MB)

    const long nx4   = (long)M * K / 4;
    const long ntot4 = nx4 + (long)N * K / 4;
    quantize_fused<<<2048, 256, 0, stream>>>((const float4*)x, (const float4*)w,
                                             (int*)qx, amax, amax_w, nx4, ntot4);

    dim3 grid(N / 256, M / 256);               // (16, 32) = 512 blocks
    gemm_i8_2phase<<<grid, 512, 0, stream>>>(qx, qw, bias, amax, amax_w, out, M, N, K);
}